// Round 8
// baseline (618.661 us; speedup 1.0000x reference)
//
#include <hip/hip_runtime.h>
#include <math.h>

// LiquidNet2: B=1024, I=128, S=512, UNFOLDS=6, out v[B,S] fp32.
//
// Block = postsynaptic neuron j (512 blocks), thread = batch PAIR (512 thr).
// ZERO transcendentals: packed software exp2 + packed Newton reciprocal.
//   t(pair)  = pk_fma(AC, v, AC)          (op_sel broadcast: A*v + C)
//   z = pk_add(t, 1.5*2^23)               (RNE -> k = round(t) in low bits)
//   kf = pk_add(z, -magic); f = pk_fma(kf, -1, t)      f in [-0.5, 0.5]
//   p = Horner4(f)  (4 pk_fma, Taylor e^{f ln2})
//   scale = bits: (zbits<<23) + 0x3F800000  (2 x v_lshl_add_u32)
//   e = pk_mul(p, scale);  d = pk_add(e, 1)
//   y0 = bit-trick (0x7EF311C3 - bits(d));  s' = y0*(d*y0 - 2) = -1/d (1 NR)
//   n += (-Wn)*s' ; den += (-Wp)*s'        (weights pre-negated in prep)
// Params as float4 records (A,C,-Wn,-Wp) in [j][i] order -> s_load dwordx4.
// A=-sigma*log2e, C=sigma*mu*log2e, Wn=W*erev, Wp=W.
// v transposed vT[S][B]; 6 stream-ordered unfold launches ping-ponging vT.

#define B_TOT 1024
#define I_DIM 128
#define S_DIM 512
#define UNFOLDS 6
#define L2E 1.4426950408889634f

typedef float v2f __attribute__((ext_vector_type(2)));

// ---- ws layout (floats); vB overlays sensQ+xT (dead after sensory) ----
#define OFF_RECQ 0                                   // 512*512*4  = 4 MiB
#define OFF_VA   (OFF_RECQ + S_DIM * S_DIM * 4)      // 512*1024   = 2 MiB
#define OFF_SN   (OFF_VA + S_DIM * B_TOT)            // 2 MiB
#define OFF_SD   (OFF_SN + S_DIM * B_TOT)            // 2 MiB
#define OFF_SENQ (OFF_SD + S_DIM * B_TOT)            // 512*128*4  = 1 MiB
#define OFF_XT   (OFF_SENQ + S_DIM * I_DIM * 4)      // 128*1024   = 0.5 MiB
#define OFF_VB   OFF_SENQ                            // 2 MiB overlay
// total = 12.0 MiB

__device__ __forceinline__ v2f pk_add(v2f a, v2f b) {
    v2f r; asm("v_pk_add_f32 %0, %1, %2" : "=v"(r) : "v"(a), "v"(b)); return r;
}
__device__ __forceinline__ v2f pk_mul(v2f a, v2f b) {
    v2f r; asm("v_pk_mul_f32 %0, %1, %2" : "=v"(r) : "v"(a), "v"(b)); return r;
}
__device__ __forceinline__ v2f pk_fma(v2f a, v2f b, v2f c) {
    v2f r; asm("v_pk_fma_f32 %0, %1, %2, %3" : "=v"(r) : "v"(a), "v"(b), "v"(c)); return r;
}

struct PkC {
    v2f magic, negmagic, mone, mtwo, one, c1, c2, c3, c4;
};
__device__ __forceinline__ PkC make_pkc() {
    PkC K;
    K.magic    = (v2f){12582912.0f, 12582912.0f};     // 1.5 * 2^23
    K.negmagic = (v2f){-12582912.0f, -12582912.0f};
    K.mone     = (v2f){-1.0f, -1.0f};
    K.mtwo     = (v2f){-2.0f, -2.0f};
    K.one      = (v2f){1.0f, 1.0f};
    K.c1       = (v2f){0.69314718f, 0.69314718f};     // ln2
    K.c2       = (v2f){0.24022651f, 0.24022651f};     // ln2^2/2
    K.c3       = (v2f){0.05550411f, 0.05550411f};     // ln2^3/6
    K.c4       = (v2f){0.00967781f, 0.00967781f};     // ln2^4/24
    return K;
}

// one packed sigmoid step: 2 elements (batch pair), no trans ops
__device__ __forceinline__ void sig_step(v2f ac, v2f ww, v2f v,
                                         const PkC& K, v2f& n, v2f& den)
{
    v2f t;
    // t.lo = ac.lo*v.lo + ac.hi ; t.hi = ac.lo*v.hi + ac.hi
    asm("v_pk_fma_f32 %0, %1, %2, %1 op_sel:[0,0,1] op_sel_hi:[0,1,1]"
        : "=v"(t) : "v"(ac), "v"(v));
    v2f z  = pk_add(t, K.magic);          // k = round(t) via RNE
    v2f kf = pk_add(z, K.negmagic);       // kf = (float)k
    v2f f  = pk_fma(kf, K.mone, t);       // f = t - k, in [-0.5, 0.5]
    // p = 2^f  (Taylor deg-4, Horner)
    v2f p = pk_fma(K.c4, f, K.c3);
    p = pk_fma(p, f, K.c2);
    p = pk_fma(p, f, K.c1);
    p = pk_fma(p, f, K.one);
    // scale = 2^k from z's low bits: (zbits<<23) + 0x3F800000
    unsigned zx = __float_as_uint(z.x), zy = __float_as_uint(z.y);
    v2f sc;
    sc.x = __uint_as_float((zx << 23) + 0x3F800000u);
    sc.y = __uint_as_float((zy << 23) + 0x3F800000u);
    v2f e  = pk_mul(p, sc);               // 2^t
    v2f dd = pk_add(e, K.one);            // 1 + 2^t
    // reciprocal: bit-trick + 1 Newton, sign-flipped (s = -1/dd)
    v2f y;
    y.x = __uint_as_float(0x7EF311C3u - __float_as_uint(dd.x));
    y.y = __uint_as_float(0x7EF311C3u - __float_as_uint(dd.y));
    v2f q = pk_fma(dd, y, K.mtwo);        // dd*y - 2
    v2f s = pk_mul(y, q);                 // y*(dd*y-2) = -(1/dd)
    // accumulate; ww = (-Wn, -Wp) so signs come out right
    asm("v_pk_fma_f32 %0, %1, %2, %0 op_sel:[0,0,0] op_sel_hi:[0,1,1]"
        : "+v"(n) : "v"(ww), "v"(s));
    asm("v_pk_fma_f32 %0, %1, %2, %0 op_sel:[1,0,0] op_sel_hi:[1,1,1]"
        : "+v"(den) : "v"(ww), "v"(s));
}

__device__ __forceinline__ void col_reduce_pk(
    const float4* __restrict__ qp,   // [nd] records for this j
    const float* __restrict__ vsrc,  // [nd][B_TOT]
    int nd, int tb, const PkC& K, v2f& n, v2f& d)
{
    #pragma unroll 8
    for (int i = 0; i < nd; ++i) {
        float4 q = qp[i];                         // block-uniform -> s_load
        v2f ac; ac.x = q.x; ac.y = q.y;
        v2f ww; ww.x = q.z; ww.y = q.w;
        v2f v = *(const v2f*)(vsrc + (size_t)i * B_TOT + tb);
        sig_step(ac, ww, v, K, n, d);
    }
}

// ---------------- prep: param transform + transposes ----------------
__global__ __launch_bounds__(256) void prep_all(
    const float* __restrict__ inputs, const float* __restrict__ hx,
    const float* __restrict__ input_w, const float* __restrict__ input_b,
    const float* __restrict__ s_mu, const float* __restrict__ s_sigma,
    const float* __restrict__ s_W, const float* __restrict__ s_erev,
    const float* __restrict__ mu, const float* __restrict__ sigma,
    const float* __restrict__ W, const float* __restrict__ erev,
    float* __restrict__ ws)
{
    __shared__ float tA[32][33], tB[32][33], tC[32][33];
    const int bid = blockIdx.x;
    const int tx = threadIdx.x & 31, ty = threadIdx.x >> 5;   // 32 x 8

    if (bid < 320) {
        // params: src [i][j] row-major -> dst [j][i] float4 (A,C,-Wn,-Wp)
        bool rec = bid < 256;
        int b2  = rec ? bid : bid - 256;
        int tri = b2 >> 4;            // i-tile
        int tcj = b2 & 15;            // j-tile
        const float* sgp = rec ? sigma : s_sigma;
        const float* mup = rec ? mu    : s_mu;
        const float* wp  = rec ? W     : s_W;
        const float* erp = rec ? erev  : s_erev;
        #pragma unroll
        for (int rr = 0; rr < 4; ++rr) {
            int r = ty + rr * 8;
            int idx = (tri * 32 + r) * S_DIM + tcj * 32 + tx;
            float sg = sgp[idx], m = mup[idx], w = wp[idx], er = erp[idx];
            tA[r][tx] = -sg * L2E;
            tB[r][tx] = sg * m * L2E;
            tC[r][tx] = w * er;
        }
        __syncthreads();
        float4* dst = (float4*)(ws + (rec ? OFF_RECQ : OFF_SENQ));
        int ld = rec ? S_DIM : I_DIM;
        #pragma unroll
        for (int rr = 0; rr < 4; ++rr) {
            int jj = ty + rr * 8;
            float wn = tC[tx][jj];
            dst[(tcj * 32 + jj) * ld + tri * 32 + tx] =
                make_float4(tA[tx][jj], tB[tx][jj], -wn, -fabsf(wn));
        }
    } else if (bid < 448) {
        // xT[i][b] = inputs[b][i]*w[i]+b[i]
        int b2 = bid - 320;
        int tbr = b2 >> 2, tci = b2 & 3;
        int i = tci * 32 + tx;
        float wi = input_w[i], bi = input_b[i];
        #pragma unroll
        for (int rr = 0; rr < 4; ++rr) {
            int r = ty + rr * 8;
            tA[r][tx] = inputs[(tbr * 32 + r) * I_DIM + i] * wi + bi;
        }
        __syncthreads();
        float* xT = ws + OFF_XT;
        #pragma unroll
        for (int rr = 0; rr < 4; ++rr) {
            int ii = ty + rr * 8;
            xT[(tci * 32 + ii) * B_TOT + tbr * 32 + tx] = tA[tx][ii];
        }
    } else {
        // vA[j][b] = hx[b][j]
        int b2 = bid - 448;
        int tbr = b2 >> 4, tcj = b2 & 15;
        #pragma unroll
        for (int rr = 0; rr < 4; ++rr) {
            int r = ty + rr * 8;
            tA[r][tx] = hx[(tbr * 32 + r) * S_DIM + tcj * 32 + tx];
        }
        __syncthreads();
        float* vA = ws + OFF_VA;
        #pragma unroll
        for (int rr = 0; rr < 4; ++rr) {
            int jj = ty + rr * 8;
            vA[(tcj * 32 + jj) * B_TOT + tbr * 32 + tx] = tA[tx][jj];
        }
    }
}

// ---------------- sensory (once) ----------------
__global__ __launch_bounds__(512, 4) void sensory_kernel(float* __restrict__ ws)
{
    const int j = blockIdx.x;
    const int tb = threadIdx.x * 2;
    PkC K = make_pkc();
    v2f n; n.x = 0.f; n.y = 0.f;
    v2f d; d.x = 0.f; d.y = 0.f;
    col_reduce_pk((const float4*)(ws + OFF_SENQ) + j * I_DIM,
                  ws + OFF_XT, I_DIM, tb, K, n, d);
    *(v2f*)&ws[OFF_SN + j * B_TOT + tb] = n;
    *(v2f*)&ws[OFF_SD + j * B_TOT + tb] = d;
}

// ---------------- one unfold ----------------
__global__ __launch_bounds__(512, 4) void unfold_kernel(
    const float* __restrict__ ws, const float* __restrict__ vsrc,
    float* __restrict__ vdst,
    const float* __restrict__ gleak, const float* __restrict__ vleak,
    const float* __restrict__ cm_t,
    float* __restrict__ out, int write_out)
{
    const int j = blockIdx.x;
    const int tb = threadIdx.x * 2;
    PkC K = make_pkc();
    v2f n = *(const v2f*)&ws[OFF_SN + j * B_TOT + tb];   // init with sensory
    v2f d = *(const v2f*)&ws[OFF_SD + j * B_TOT + tb];
    col_reduce_pk((const float4*)(ws + OFF_RECQ) + j * S_DIM,
                  vsrc, S_DIM, tb, K, n, d);

    v2f vo = *(const v2f*)&vsrc[j * B_TOT + tb];
    float gl = gleak[j], vl = vleak[j], cm = cm_t[j];
    float glvl = gl * vl, cg = cm + gl;

    float r0 = (fmaf(cm, vo.x, glvl) + n.x) / (cg + d.x);
    float r1 = (fmaf(cm, vo.y, glvl) + n.y) / (cg + d.y);

    if (write_out) {
        out[tb * S_DIM + j] = r0;
        out[(tb + 1) * S_DIM + j] = r1;
    } else {
        v2f rr; rr.x = r0; rr.y = r1;
        *(v2f*)&vdst[j * B_TOT + tb] = rr;
    }
}

extern "C" void kernel_launch(void* const* d_in, const int* in_sizes, int n_in,
                              void* d_out, int out_size, void* d_ws, size_t ws_size,
                              hipStream_t stream) {
    const float* inputs   = (const float*)d_in[0];
    const float* hx       = (const float*)d_in[1];
    const float* input_w  = (const float*)d_in[2];
    const float* input_b  = (const float*)d_in[3];
    const float* s_mu     = (const float*)d_in[4];
    const float* s_sigma  = (const float*)d_in[5];
    const float* s_W      = (const float*)d_in[6];
    const float* s_erev   = (const float*)d_in[7];
    const float* mu       = (const float*)d_in[8];
    const float* sigma    = (const float*)d_in[9];
    const float* W        = (const float*)d_in[10];
    const float* erev     = (const float*)d_in[11];
    const float* vleak    = (const float*)d_in[12];
    const float* gleak    = (const float*)d_in[13];
    const float* cm_t     = (const float*)d_in[14];
    float* out = (float*)d_out;
    float* ws  = (float*)d_ws;

    prep_all<<<960, 256, 0, stream>>>(inputs, hx, input_w, input_b,
                                      s_mu, s_sigma, s_W, s_erev,
                                      mu, sigma, W, erev, ws);

    sensory_kernel<<<S_DIM, 512, 0, stream>>>(ws);

    float* vA = ws + OFF_VA;
    float* vB = ws + OFF_VB;
    for (int u = 0; u < UNFOLDS; ++u) {
        const float* src = (u & 1) ? vB : vA;
        float* dst       = (u & 1) ? vA : vB;
        int last = (u == UNFOLDS - 1);
        unfold_kernel<<<S_DIM, 512, 0, stream>>>(
            ws, src, dst, gleak, vleak, cm_t, out, last);
    }
}

// Round 9
// 432.536 us; speedup vs baseline: 1.4303x; 1.4303x over previous
//
#include <hip/hip_runtime.h>
#include <hip/hip_fp16.h>
#include <math.h>

// LiquidNet2: B=1024, I=128, S=512, UNFOLDS=6, out v[B,S] fp32.
//
// Block = postsynaptic neuron j (512 blocks), thread = batch PAIR (512 thr).
// Params (A',C',Wn,Wp) block-uniform -> s_load float4 (SMEM pipe, free).
// Sigmoid via 64 KB LDS table (1024 entries x 16 replicas, f16 value+slope,
// linear interp):
//   f = A'*v + C'  (A' = -sigma*log2e*SCALE, C' = sigma*mu*log2e*SCALE + 512)
//   f = med3(f, 0, 1023); k = (u32)f; fr = fract(f)
//   entry(k, rep=lane&15) at byte k*64 + rep*4; 4 lanes/rep over 2 banks ->
//   ~2-way aliasing (free).  s = v_fma_mix(slope_f16, fr, value_f16).
//   n += Wn*s; d += Wp*s  (full-f32 weights, v_fmac with SGPR operand).
// 64 KB LDS -> 2 blocks/CU (16 waves, 4/SIMD): VALU-issue (~36us) overlaps
// the per-CU DS gather pipe (~40us) instead of serializing with trans ops.
// v transposed vT[S][B]; 6 stream-ordered unfold launches ping-ponging vT.

#define B_TOT 1024
#define I_DIM 128
#define S_DIM 512
#define UNFOLDS 6
#define L2E 1.4426950408889634f
#define TBL_N 1024
#define NREP 16
#define T_MAX 14.0f

// ---- ws layout (floats); vB overlays sensQ+xT (dead after sensory) ----
#define OFF_RECQ 0                                   // 512*512*4  = 4 MiB
#define OFF_VA   (OFF_RECQ + S_DIM * S_DIM * 4)      // 512*1024   = 2 MiB
#define OFF_SN   (OFF_VA + S_DIM * B_TOT)            // 2 MiB
#define OFF_SD   (OFF_SN + S_DIM * B_TOT)            // 2 MiB
#define OFF_SENQ (OFF_SD + S_DIM * B_TOT)            // 512*128*4  = 1 MiB
#define OFF_XT   (OFF_SENQ + S_DIM * I_DIM * 4)      // 128*1024   = 0.5 MiB
#define OFF_VB   OFF_SENQ                            // 2 MiB overlay
// total = 12.0 MiB

__device__ __forceinline__ float ffract(float x) {
#if __has_builtin(__builtin_amdgcn_fractf)
    return __builtin_amdgcn_fractf(x);
#else
    return x - floorf(x);
#endif
}

// ---------------- prep: param transform + transposes ----------------
__global__ __launch_bounds__(256) void prep_all(
    const float* __restrict__ inputs, const float* __restrict__ hx,
    const float* __restrict__ input_w, const float* __restrict__ input_b,
    const float* __restrict__ s_mu, const float* __restrict__ s_sigma,
    const float* __restrict__ s_W, const float* __restrict__ s_erev,
    const float* __restrict__ mu, const float* __restrict__ sigma,
    const float* __restrict__ W, const float* __restrict__ erev,
    float* __restrict__ ws)
{
    __shared__ float tA[32][33], tB[32][33], tC[32][33];
    const int bid = blockIdx.x;
    const int tx = threadIdx.x & 31, ty = threadIdx.x >> 5;   // 32 x 8
    const float SCALE = (float)TBL_N / (2.0f * T_MAX);        // 36.5714
    const float OFF   = (float)(TBL_N / 2);                   // 512 (left edge)

    if (bid < 320) {
        // params: src [i][j] row-major -> dst [j][i] float4 (A',C',Wn,Wp)
        bool rec = bid < 256;
        int b2  = rec ? bid : bid - 256;
        int tri = b2 >> 4;            // i-tile
        int tcj = b2 & 15;            // j-tile
        const float* sgp = rec ? sigma : s_sigma;
        const float* mup = rec ? mu    : s_mu;
        const float* wp  = rec ? W     : s_W;
        const float* erp = rec ? erev  : s_erev;
        #pragma unroll
        for (int rr = 0; rr < 4; ++rr) {
            int r = ty + rr * 8;
            int idx = (tri * 32 + r) * S_DIM + tcj * 32 + tx;
            float sg = sgp[idx], m = mup[idx], w = wp[idx], er = erp[idx];
            tA[r][tx] = -sg * L2E * SCALE;
            tB[r][tx] = sg * m * L2E * SCALE + OFF;
            tC[r][tx] = w * er;
        }
        __syncthreads();
        float4* dst = (float4*)(ws + (rec ? OFF_RECQ : OFF_SENQ));
        int ld = rec ? S_DIM : I_DIM;
        #pragma unroll
        for (int rr = 0; rr < 4; ++rr) {
            int jj = ty + rr * 8;
            float wn = tC[tx][jj];
            dst[(tcj * 32 + jj) * ld + tri * 32 + tx] =
                make_float4(tA[tx][jj], tB[tx][jj], wn, fabsf(wn));
        }
    } else if (bid < 448) {
        // xT[i][b] = inputs[b][i]*w[i]+b[i]
        int b2 = bid - 320;
        int tbr = b2 >> 2, tci = b2 & 3;
        int i = tci * 32 + tx;
        float wi = input_w[i], bi = input_b[i];
        #pragma unroll
        for (int rr = 0; rr < 4; ++rr) {
            int r = ty + rr * 8;
            tA[r][tx] = inputs[(tbr * 32 + r) * I_DIM + i] * wi + bi;
        }
        __syncthreads();
        float* xT = ws + OFF_XT;
        #pragma unroll
        for (int rr = 0; rr < 4; ++rr) {
            int ii = ty + rr * 8;
            xT[(tci * 32 + ii) * B_TOT + tbr * 32 + tx] = tA[tx][ii];
        }
    } else {
        // vA[j][b] = hx[b][j]
        int b2 = bid - 448;
        int tbr = b2 >> 4, tcj = b2 & 15;
        #pragma unroll
        for (int rr = 0; rr < 4; ++rr) {
            int r = ty + rr * 8;
            tA[r][tx] = hx[(tbr * 32 + r) * S_DIM + tcj * 32 + tx];
        }
        __syncthreads();
        float* vA = ws + OFF_VA;
        #pragma unroll
        for (int rr = 0; rr < 4; ++rr) {
            int jj = ty + rr * 8;
            vA[(tcj * 32 + jj) * B_TOT + tbr * 32 + tx] = tA[tx][jj];
        }
    }
}

// ---------------- table build (per block) ----------------
__device__ __forceinline__ void build_tbl(unsigned* tbl, int tid)
{
    const float hb = (2.0f * T_MAX) / (float)TBL_N;
    for (int k = tid; k < TBL_N; k += 512) {
        float t0 = (float)(k - TBL_N / 2) * hb;
        float s0 = 1.0f / (1.0f + exp2f(t0));
        float s1 = 1.0f / (1.0f + exp2f(t0 + hb));
        __half2 h = __floats2half2_rn(s0, s1 - s0);
        unsigned e = __builtin_bit_cast(unsigned, h);
        #pragma unroll
        for (int r = 0; r < NREP; ++r)
            tbl[k * NREP + ((tid + r) & (NREP - 1))] = e;
    }
}

// one element: table sigmoid + accumulate (f32 weights via SGPR fmac)
__device__ __forceinline__ void sig_elem(float A, float C, float Wn, float Wp,
                                         float v, const char* tbase, float CLHI,
                                         float& n, float& d)
{
    float f = fmaf(A, v, C);
    f = __builtin_amdgcn_fmed3f(f, 0.0f, CLHI);
    unsigned k = (unsigned)f;            // trunc = floor (f >= 0)
    float fr = ffract(f);
    unsigned hv = *(const unsigned*)(tbase + (k << 6));   // k*NREP*4
    float s;
    asm("v_fma_mix_f32 %0, %1, %2, %1 op_sel:[1,0,0] op_sel_hi:[1,0,1]"
        : "=v"(s) : "v"(hv), "v"(fr));   // s = slope*fr + value
    n = fmaf(Wn, s, n);
    d = fmaf(Wp, s, d);
}

__device__ __forceinline__ void col_reduce_tbl(
    const float4* __restrict__ qp,   // [nd] records for this j (uniform)
    const float* __restrict__ vsrc,  // [nd][B_TOT]
    int nd, int tb, const char* tbase, float CLHI,
    float& n0, float& n1, float& d0, float& d1)
{
    #pragma unroll 8
    for (int i = 0; i < nd; ++i) {
        float4 q = qp[i];                         // block-uniform -> s_load
        float2 v = *(const float2*)(vsrc + (size_t)i * B_TOT + tb);
        sig_elem(q.x, q.y, q.z, q.w, v.x, tbase, CLHI, n0, d0);
        sig_elem(q.x, q.y, q.z, q.w, v.y, tbase, CLHI, n1, d1);
    }
}

// ---------------- sensory (once) ----------------
__global__ __launch_bounds__(512, 4) void sensory_kernel(float* __restrict__ ws)
{
    __shared__ unsigned tbl[TBL_N * NREP];        // 64 KB
    const int tid = threadIdx.x;
    const int j = blockIdx.x;
    const int tb = tid * 2;
    build_tbl(tbl, tid);
    __syncthreads();
    const char* tbase = (const char*)tbl + ((tid & (NREP - 1)) << 2);
    const float CLHI = (float)(TBL_N - 1);
    float n0 = 0.f, n1 = 0.f, d0 = 0.f, d1 = 0.f;
    col_reduce_tbl((const float4*)(ws + OFF_SENQ) + j * I_DIM,
                   ws + OFF_XT, I_DIM, tb, tbase, CLHI, n0, n1, d0, d1);
    *(float2*)&ws[OFF_SN + j * B_TOT + tb] = make_float2(n0, n1);
    *(float2*)&ws[OFF_SD + j * B_TOT + tb] = make_float2(d0, d1);
}

// ---------------- one unfold ----------------
__global__ __launch_bounds__(512, 4) void unfold_kernel(
    const float* __restrict__ ws, const float* __restrict__ vsrc,
    float* __restrict__ vdst,
    const float* __restrict__ gleak, const float* __restrict__ vleak,
    const float* __restrict__ cm_t,
    float* __restrict__ out, int write_out)
{
    __shared__ unsigned tbl[TBL_N * NREP];        // 64 KB
    const int tid = threadIdx.x;
    const int j = blockIdx.x;
    const int tb = tid * 2;
    build_tbl(tbl, tid);
    __syncthreads();
    const char* tbase = (const char*)tbl + ((tid & (NREP - 1)) << 2);
    const float CLHI = (float)(TBL_N - 1);

    float2 sn = *(const float2*)&ws[OFF_SN + j * B_TOT + tb];
    float2 sd = *(const float2*)&ws[OFF_SD + j * B_TOT + tb];
    float n0 = sn.x, n1 = sn.y, d0 = sd.x, d1 = sd.y;
    col_reduce_tbl((const float4*)(ws + OFF_RECQ) + j * S_DIM,
                   vsrc, S_DIM, tb, tbase, CLHI, n0, n1, d0, d1);

    float2 vo = *(const float2*)&vsrc[j * B_TOT + tb];
    float gl = gleak[j], vl = vleak[j], cm = cm_t[j];
    float glvl = gl * vl, cg = cm + gl;

    float r0 = (fmaf(cm, vo.x, glvl) + n0) / (cg + d0);
    float r1 = (fmaf(cm, vo.y, glvl) + n1) / (cg + d1);

    if (write_out) {
        out[tb * S_DIM + j] = r0;
        out[(tb + 1) * S_DIM + j] = r1;
    } else {
        *(float2*)&vdst[j * B_TOT + tb] = make_float2(r0, r1);
    }
}

extern "C" void kernel_launch(void* const* d_in, const int* in_sizes, int n_in,
                              void* d_out, int out_size, void* d_ws, size_t ws_size,
                              hipStream_t stream) {
    const float* inputs   = (const float*)d_in[0];
    const float* hx       = (const float*)d_in[1];
    const float* input_w  = (const float*)d_in[2];
    const float* input_b  = (const float*)d_in[3];
    const float* s_mu     = (const float*)d_in[4];
    const float* s_sigma  = (const float*)d_in[5];
    const float* s_W      = (const float*)d_in[6];
    const float* s_erev   = (const float*)d_in[7];
    const float* mu       = (const float*)d_in[8];
    const float* sigma    = (const float*)d_in[9];
    const float* W        = (const float*)d_in[10];
    const float* erev     = (const float*)d_in[11];
    const float* vleak    = (const float*)d_in[12];
    const float* gleak    = (const float*)d_in[13];
    const float* cm_t     = (const float*)d_in[14];
    float* out = (float*)d_out;
    float* ws  = (float*)d_ws;

    prep_all<<<960, 256, 0, stream>>>(inputs, hx, input_w, input_b,
                                      s_mu, s_sigma, s_W, s_erev,
                                      mu, sigma, W, erev, ws);

    sensory_kernel<<<S_DIM, 512, 0, stream>>>(ws);

    float* vA = ws + OFF_VA;
    float* vB = ws + OFF_VB;
    for (int u = 0; u < UNFOLDS; ++u) {
        const float* src = (u & 1) ? vB : vA;
        float* dst       = (u & 1) ? vA : vB;
        int last = (u == UNFOLDS - 1);
        unfold_kernel<<<S_DIM, 512, 0, stream>>>(
            ws, src, dst, gleak, vleak, cm_t, out, last);
    }
}